// Round 6
// baseline (335.205 us; speedup 1.0000x reference)
//
#include <hip/hip_runtime.h>
#include <math.h>

// TIME_WARPING: not-a-knot cubic spline fit + warped resample, fused.
//
// Math (identical to harness-verified versions): spline A M = rhs with
//   M1 = y0-2y1+y2 (exact), MS2 = y[S-3]-2y[S-2]+y[S-1] (exact),
//   M0 = 2M1-M2, M[S-1] = 2MS2-M[S-3]; interior Toeplitz(1,4,1) inverse =
//   conv with G(k) = (-1)^k r^k/(2 sqrt3), r = 2-sqrt(3), truncated W=8.
//   Interior M == 19-tap conv of y with H = 6*(G (*) [1,-2,1]).
//   Near-boundary M: f-based conv + image corrections (ghost v1/vS2).
//
// R6: INPUT-SPACE TRANSPOSE (post-mortem R0-R5: duration ~= sum of component
// times, no slack; the biggest removable component is pass D's scattered LDS
// gathers + conflicts ~2700cy/signal):
//  * Each thread owns 4 consecutive INPUT intervals [i0,i0+4), i0=4t+1024s.
//    It computes M[i0..i0+4] (5 convs, +25% vs R3 -- not R5's +50%+selects),
//    builds each interval's cubic coeffs ONCE (R3 rebuilt them per output),
//    and writes the outputs j with floor(j*sc) in its intervals.
//    -> pass D LDS gathers: GONE (operands live in the conv window regs).
//    -> sm[] + its writes + 2nd barrier: GONE. LDS = 16KB (sy only).
//  * Exact ownership: jstart(i) = min{ j : fl(j*sc) >= i } via seeded fixup
//    loops -- bitwise deterministic across threads, so the output partition
//    is exact and t = fl(j*sc) - i matches the reference rounding exactly.
//  * Clamped tail (j*sc >= 4095 -> w=4095, t=1 -> value y[S-1]): written
//    cooperatively by all threads (avoids one thread owning ~950 outputs).
//  * Empty-range threads (sc<1 high-i0) skip conv+window entirely (whole-wave
//    execz skips -- contiguous region).

#define SLEN 4096
#define WRAD 8
#define BLK  256

typedef float f32x4 __attribute__((ext_vector_type(4)));

// smallest j >= 0 with (float)j*sc >= (float)i  (exact; seed + fixup)
__device__ __forceinline__ int jstart_f(int i, float sc, float inv) {
    const float fi = (float)i;
    int js = (int)ceilf(fi * inv);
    if (js < 0) js = 0;
    while ((float)js * sc < fi) ++js;
    while (js > 0 && (float)(js - 1) * sc >= fi) --js;
    return js;
}

// ---- cold path: near-boundary interval groups (exact f-based M + images) ----
__device__ __attribute__((noinline))
void edge_group(const float* __restrict__ sy, float* __restrict__ o,
                int i0, float sc, float inv, int jcap)
{
    int a  = jstart_f(i0, sc, inv);     if (a  > jcap) a  = jcap;
    int a4 = jstart_f(i0 + 4, sc, inv); if (a4 > jcap) a4 = jcap;
    if (a >= a4) return;

    const float log2r = -1.8999686269529532f;  // log2(2 - sqrt(3))
    const float r = 0.26794919243112270f;
    float G[WRAD + 1];
    G[0] = 0.28867513459481287f;               // 1/(2 sqrt 3)
    #pragma unroll
    for (int k = 1; k <= WRAD; ++k) G[k] = -G[k - 1] * r;

    const float M1  = sy[0]        - 2.0f * sy[1]        + sy[2];
    const float MS2 = sy[SLEN - 3] - 2.0f * sy[SLEN - 2] + sy[SLEN - 1];

    float v1 = 0.0f, vS2 = 0.0f;
    #pragma unroll
    for (int k = 1; k <= WRAD; ++k) {
        const int ja = 1 + k;                               // 2..9
        float fa = 6.0f * (sy[ja - 1] - 2.0f * sy[ja] + sy[ja + 1]);
        if (ja == 2) fa -= M1;
        v1 += G[k] * fa;
        const int jb = SLEN - 2 - k;                        // S-3..S-10
        float fb = 6.0f * (sy[jb - 1] - 2.0f * sy[jb] + sy[jb + 1]);
        if (jb == SLEN - 3) fb -= MS2;
        vS2 += G[k] * fb;
    }

    auto Mconv = [&](int i) -> float {                      // valid 2 <= i <= S-3
        float acc = 0.0f;
        #pragma unroll
        for (int k = -WRAD; k <= WRAD; ++k) {
            const int j = i + k;
            float fj = 0.0f;
            if (j >= 2 && j <= SLEN - 3) {
                fj = 6.0f * (sy[j - 1] - 2.0f * sy[j] + sy[j + 1]);
                if (j == 2)        fj -= M1;
                if (j == SLEN - 3) fj -= MS2;
            }
            acc += G[k < 0 ? -k : k] * fj;
        }
        if (i <= 34) {
            float cc = v1 * exp2f((float)(i - 1) * log2r);
            acc += (i & 1) ? -cc : cc;
        }
        if (i >= SLEN - 36) {
            float cc = vS2 * exp2f((float)(SLEN - 2 - i) * log2r);
            acc += (i & 1) ? cc : -cc;
        }
        return acc;
    };
    auto Mfull = [&](int i) -> float {
        if (i == 1)        return M1;
        if (i == SLEN - 2) return MS2;
        if (i == 0)        return 2.0f * M1  - Mconv(2);
        if (i == SLEN - 1) return 2.0f * MS2 - Mconv(SLEN - 3);
        return Mconv(i);
    };

    float Ms[5];
    #pragma unroll
    for (int k = 0; k < 5; ++k) {
        int ik = i0 + k; if (ik > SLEN - 1) ik = SLEN - 1;  // guard (unused when clamped)
        Ms[k] = Mfull(ik);
    }

    #pragma unroll
    for (int k = 0; k < 4; ++k) {
        int bnd = jstart_f(i0 + k + 1, sc, inv); if (bnd > jcap) bnd = jcap;
        const int iy0 = i0 + k;
        const int iy1 = (iy0 + 1 > SLEN - 1) ? SLEN - 1 : iy0 + 1;  // guard
        const float y0 = sy[iy0 > SLEN - 1 ? SLEN - 1 : iy0];
        const float y1 = sy[iy1];
        const float m0 = Ms[k], m1 = Ms[k + 1];
        const float bb = (y1 - y0) - (2.0f * m0 + m1) * (1.0f / 6.0f);
        const float cf = 0.5f * m0;
        const float dd = (m1 - m0) * (1.0f / 6.0f);
        for (int j = a; j < bnd; ++j) {
            const float w  = (float)j * sc;                 // < jcap => no clamp
            const float tt = w - (float)(i0 + k);           // exact (Sterbenz)
            __builtin_nontemporal_store(y0 + tt * (bb + tt * (cf + tt * dd)), &o[j]);
        }
        a = bnd;
    }
}

__global__ __launch_bounds__(BLK, 5) void time_warp_kernel(
    const float* __restrict__ x,
    const float* __restrict__ scale,
    const int*   __restrict__ apply_mask,
    float* __restrict__ out,
    int C)
{
    __shared__ float sy[SLEN];                 // 16384 B total LDS

    const int bid = blockIdx.x;                // = b*C + c
    const int b   = bid / C;
    const int t   = threadIdx.x;
    const float* __restrict__ xin = x   + (size_t)bid * SLEN;
    float*       __restrict__ o   = out + (size_t)bid * SLEN;

    // per-sample apply decision (block-uniform, before any barrier)
    if (apply_mask[b] == 0) {
        const f32x4* __restrict__ xi4 = (const f32x4*)xin;
        f32x4*       __restrict__ o4  = (f32x4*)o;
        #pragma unroll
        for (int k = 0; k < 4; ++k) {
            f32x4 v = xi4[t + BLK * k];
            __builtin_nontemporal_store(v, &o4[t + BLK * k]);
        }
        return;
    }

    // stage y into LDS (coalesced float4 -> ds_write_b128)
    {
        const float4* __restrict__ xi4 = (const float4*)xin;
        #pragma unroll
        for (int k = 0; k < 4; ++k)
            *(float4*)&sy[4 * (t + BLK * k)] = xi4[t + BLK * k];
    }
    __syncthreads();                           // the ONLY barrier

    const float sc  = scale[b];
    const float inv = 1.0f / sc;
    int jcap = jstart_f(SLEN - 1, sc, inv);    // outputs j >= jcap are clamped
    if (jcap > SLEN) jcap = SLEN;

    // H = 6*(G (*) [1,-2,1]) taps (compile-time folded)
    const float r = 0.26794919243112270f;
    float G[WRAD + 1];
    G[0] = 0.28867513459481287f;
    #pragma unroll
    for (int k = 1; k <= WRAD; ++k) G[k] = -G[k - 1] * r;
    float Hh[WRAD + 2];
    Hh[0] = 12.0f * (G[1] - G[0]);
    #pragma unroll
    for (int k = 1; k < WRAD; ++k) Hh[k] = 6.0f * (G[k - 1] - 2.0f * G[k] + G[k + 1]);
    Hh[WRAD]     = 6.0f * (G[WRAD - 1] - 2.0f * G[WRAD]);
    Hh[WRAD + 1] = 6.0f * G[WRAD];

    #pragma unroll
    for (int s = 0; s < 4; ++s) {
        const int i0 = 4 * t + 1024 * s;       // 4 consecutive input intervals
        if (i0 >= 36 && i0 <= SLEN - 44) {
            // ---- hot interior path ----
            int a  = jstart_f(i0, sc, inv);     if (a  > jcap) a  = jcap;
            int a4 = jstart_f(i0 + 4, sc, inv); if (a4 > jcap) a4 = jcap;
            if (a >= a4) continue;             // no outputs: skip window+conv

            // y window [i0-12, i0+16): 7 aligned b128 reads, lane stride 16B
            float wv[28];
            #pragma unroll
            for (int m = 0; m < 7; ++m)
                *(float4*)&wv[4 * m] = *(const float4*)&sy[i0 - 12 + 4 * m];

            // M[i0 .. i0+4] via 19-tap H-conv (y[i0+d] = wv[12+d])
            float Ms[5];
            #pragma unroll
            for (int ii = 0; ii < 5; ++ii) {
                float acc = Hh[0] * wv[12 + ii];
                #pragma unroll
                for (int k = 1; k <= WRAD + 1; ++k)
                    acc += Hh[k] * (wv[12 + ii - k] + wv[12 + ii + k]);
                Ms[ii] = acc;
            }

            #pragma unroll
            for (int k = 0; k < 4; ++k) {
                int bnd;
                if (k == 3) bnd = a4;
                else { bnd = jstart_f(i0 + k + 1, sc, inv); if (bnd > jcap) bnd = jcap; }
                const float y0 = wv[12 + k], y1 = wv[13 + k];
                const float m0 = Ms[k], m1 = Ms[k + 1];
                const float bb = (y1 - y0) - (2.0f * m0 + m1) * (1.0f / 6.0f);
                const float cf = 0.5f * m0;
                const float dd = (m1 - m0) * (1.0f / 6.0f);
                for (int j = a; j < bnd; ++j) {
                    const float w  = (float)j * sc;        // < jcap => unclamped
                    const float tt = w - (float)(i0 + k);  // exact, == reference t
                    __builtin_nontemporal_store(y0 + tt * (bb + tt * (cf + tt * dd)), &o[j]);
                }
                a = bnd;
            }
        } else {
            edge_group(sy, o, i0, sc, inv, jcap);
        }
    }

    // clamped tail: j*sc >= 4095 -> w = 4095, t = 1 -> value y[S-1]
    if (jcap < SLEN) {
        const float yS1 = sy[SLEN - 1];
        for (int j = jcap + t; j < SLEN; j += BLK)
            __builtin_nontemporal_store(yS1, &o[j]);
    }
}

extern "C" void kernel_launch(void* const* d_in, const int* in_sizes, int n_in,
                              void* d_out, int out_size, void* d_ws, size_t ws_size,
                              hipStream_t stream) {
    const float* x     = (const float*)d_in[0];
    const float* scale = (const float*)d_in[1];
    const int*   mask  = (const int*)d_in[2];
    float*       out   = (float*)d_out;

    const int B     = in_sizes[1];            // 128
    const int total = in_sizes[0];            // B*C*S
    const int C     = total / (B * SLEN);     // 64
    const int nblk  = B * C;                  // 8192

    time_warp_kernel<<<nblk, BLK, 0, stream>>>(x, scale, mask, out, C);
}

// Round 7
// 237.742 us; speedup vs baseline: 1.4100x; 1.4100x over previous
//
#include <hip/hip_runtime.h>
#include <math.h>

// TIME_WARPING: not-a-knot cubic spline fit + warped resample, fused.
//
// Math: spline A M = rhs with M1 = y0-2y1+y2 (exact), MS2 = y[S-3]-2y[S-2]+y[S-1]
//   (exact), M0 = 2M1-M2, M[S-1] = 2MS2-M[S-3]; interior Toeplitz(1,4,1) inverse
//   = conv with G(k) = (-1)^k r^k/(2 sqrt3), r = 2-sqrt(3). Interior M == conv of
//   y with H = 6*(G (*) [1,-2,1]). Edge region: exact f-based conv (W=8) + image
//   corrections (ghost v1/vS2).
//
// R7 = R3 (proven 84us/dispatch optimum) + two safe trims:
//  * 8-wide conv groups (j0 = 8t + 2048s): one 24-float window per 8 M values
//    -> 12 b128 window reads/thread (was 28). Conv VALU unchanged per M.
//  * Interior Green truncation W=6 (was 8): taps H[0..7], window [j0-8, j0+16).
//    Truncation error ~1e-3 std vs measured absmax 0.0156 and 0.108 threshold.
//    Edge path keeps W=8 exactly as harness-verified.
// Post-mortem record: R4 (persistence+prefetch) = +traffic, no gain; R5 (conv in
// gather space) = +VALU 1:1 slower; R6 (input-space transpose) = write
// amplification 2.4x + jstart VALU, -78%. Duration responds 1:1 to added VALU
// and HBM bytes; LDS/occupancy cuts have slack. This round tests a big LDS+VALU
// cut on the proven structure.

#define SLEN 4096
#define WRAD 8   // edge-path truncation (harness-verified exact path)
#define WC   6   // interior truncation
#define BLK  256

typedef float f32x4 __attribute__((ext_vector_type(4)));

__global__ __launch_bounds__(BLK, 5) void time_warp_kernel(
    const float* __restrict__ x,
    const float* __restrict__ scale,
    const int*   __restrict__ apply_mask,
    float* __restrict__ out,
    int C)
{
    __shared__ float sy[SLEN];   // input signal          (16384 B)
    __shared__ float sm[SLEN];   // second derivatives M  (16384 B) => 32768 B

    const int bid = blockIdx.x;   // = b*C + c
    const int b   = bid / C;
    const int t   = threadIdx.x;
    const float* __restrict__ xin = x   + (size_t)bid * SLEN;
    float*       __restrict__ o   = out + (size_t)bid * SLEN;

    // per-sample apply decision (block-uniform, before any barrier)
    if (apply_mask[b] == 0) {
        const f32x4* __restrict__ xi4 = (const f32x4*)xin;
        f32x4*       __restrict__ o4  = (f32x4*)o;
        #pragma unroll
        for (int k = 0; k < 4; ++k) {
            f32x4 v = xi4[t + BLK * k];
            __builtin_nontemporal_store(v, &o4[t + BLK * k]);
        }
        return;
    }

    // ---- stage y into LDS (coalesced float4 -> ds_write_b128) ----
    {
        const float4* __restrict__ xi4 = (const float4*)xin;
        #pragma unroll
        for (int k = 0; k < 4; ++k)
            *(float4*)&sy[4 * (t + BLK * k)] = xi4[t + BLK * k];
    }
    __syncthreads();

    // Green taps (compile-time folded). G used by edge path (W=8) and to build H.
    const float r = 0.26794919243112270f;  // 2 - sqrt(3)
    float G[WRAD + 1];
    G[0] = 0.28867513459481287f;           // 1 / (2 sqrt(3))
    #pragma unroll
    for (int k = 1; k <= WRAD; ++k) G[k] = -G[k - 1] * r;
    // interior taps: H = 6*(G (*) [1,-2,1]) truncated at WC
    float Hh[WC + 2];
    Hh[0] = 12.0f * (G[1] - G[0]);
    #pragma unroll
    for (int k = 1; k < WC; ++k) Hh[k] = 6.0f * (G[k - 1] - 2.0f * G[k] + G[k + 1]);
    Hh[WC]     = 6.0f * (G[WC - 1] - 2.0f * G[WC]);   // G[WC+1] treated as 0
    Hh[WC + 1] = 6.0f * G[WC];
    const float log2r = -1.8999686269529532f;  // log2(2 - sqrt(3))

    // ---- pass C: M = conv(y) -> sm, 8-wide groups ----
    #pragma unroll
    for (int s = 0; s < 2; ++s) {
        const int j0 = 8 * t + 2048 * s;       // 8 consecutive M values / group
        if (j0 >= 40 && j0 <= SLEN - 48) {
            // interior: one 24-float window [j0-8, j0+16), 6 aligned b128 reads
            float wv[24];
            #pragma unroll
            for (int m = 0; m < 6; ++m)
                *(float4*)&wv[4 * m] = *(const float4*)&sy[j0 - 8 + 4 * m];
            float Ms[8];
            #pragma unroll
            for (int ii = 0; ii < 8; ++ii) {   // y[j0+d] = wv[8+d]
                float acc = Hh[0] * wv[8 + ii];
                #pragma unroll
                for (int k = 1; k <= WC + 1; ++k)
                    acc += Hh[k] * (wv[8 + ii - k] + wv[8 + ii + k]);
                Ms[ii] = acc;
            }
            *(float4*)&sm[j0]     = make_float4(Ms[0], Ms[1], Ms[2], Ms[3]);
            *(float4*)&sm[j0 + 4] = make_float4(Ms[4], Ms[5], Ms[6], Ms[7]);
        } else {
            // edge: two 4-wide subgroups, exact f-based path (W=8) + images
            #pragma unroll
            for (int h = 0; h < 2; ++h) {
                const int j0e = j0 + 4 * h;

                const float M1  = sy[0]        - 2.0f * sy[1]        + sy[2];
                const float MS2 = sy[SLEN - 3] - 2.0f * sy[SLEN - 2] + sy[SLEN - 1];

                float v1 = 0.0f, vS2 = 0.0f;
                #pragma unroll
                for (int k = 1; k <= WRAD; ++k) {
                    const int ja = 1 + k;                        // 2..9
                    float fa = 6.0f * (sy[ja - 1] - 2.0f * sy[ja] + sy[ja + 1]);
                    if (ja == 2) fa -= M1;
                    v1 += G[k] * fa;
                    const int jb = SLEN - 2 - k;                 // S-3 .. S-10
                    float fb = 6.0f * (sy[jb - 1] - 2.0f * sy[jb] + sy[jb + 1]);
                    if (jb == SLEN - 3) fb -= MS2;
                    vS2 += G[k] * fb;
                }

                float wv[28];                  // y[j0e-12 .. j0e+15], guarded
                #pragma unroll
                for (int m = 0; m < 7; ++m) {
                    const int q = j0e - 12 + 4 * m;
                    float4 v = make_float4(0.0f, 0.0f, 0.0f, 0.0f);
                    if (q >= 0 && q <= SLEN - 4) v = *(const float4*)&sy[q];
                    *(float4*)&wv[4 * m] = v;
                }
                float fw[20];                  // f[j0e-8 .. j0e+11]
                #pragma unroll
                for (int p = 0; p < 20; ++p) {
                    const int jj = j0e + p - 8;
                    float fv = 6.0f * (wv[p + 3] - 2.0f * wv[p + 4] + wv[p + 5]);
                    if (jj < 2 || jj > SLEN - 3) fv = 0.0f;
                    if (jj == 2)        fv -= M1;
                    if (jj == SLEN - 3) fv -= MS2;
                    fw[p] = fv;
                }
                float mv[4];
                #pragma unroll
                for (int e = 0; e < 4; ++e) {
                    float acc = G[0] * fw[8 + e];
                    #pragma unroll
                    for (int k = 1; k <= WRAD; ++k)
                        acc += G[k] * (fw[8 + e - k] + fw[8 + e + k]);
                    const int i = j0e + e;
                    if (i >= 2 && i <= 34) {
                        float cc = v1 * exp2f((float)(i - 1) * log2r);
                        acc += (i & 1) ? -cc : cc;
                    }
                    if (i >= SLEN - 36 && i <= SLEN - 3) {
                        float cc = vS2 * exp2f((float)(SLEN - 2 - i) * log2r);
                        acc += (i & 1) ? cc : -cc;
                    }
                    mv[e] = acc;
                }
                if (j0e == 0)        { mv[1] = M1;  mv[0] = 2.0f * M1  - mv[2]; }
                if (j0e == SLEN - 4) { mv[2] = MS2; mv[3] = 2.0f * MS2 - mv[1]; }
                *(float4*)&sm[j0e] = make_float4(mv[0], mv[1], mv[2], mv[3]);
            }
        }
    }
    __syncthreads();

    // ---- pass D: warped evaluation, interleaved mapping j = t + 256*q ----
    // consecutive lanes -> consecutive idx => ~2 lanes/bank on the LDS gathers
    // (ds_read2_b32 pairs); scalar NT stores are perfectly coalesced (256B/wave).
    const float sc = scale[b];
    #pragma unroll
    for (int q = 0; q < 16; ++q) {
        const int j = t + BLK * q;
        float w = fminf((float)j * sc, (float)(SLEN - 1));
        int idx = (int)w;
        if (idx > SLEN - 2) idx = SLEN - 2;
        const float tt  = w - (float)idx;
        const float y0  = sy[idx];
        const float y1  = sy[idx + 1];
        const float m0  = sm[idx];
        const float m1v = sm[idx + 1];
        const float bb = (y1 - y0) - (2.0f * m0 + m1v) * (1.0f / 6.0f);
        const float cc = 0.5f * m0;
        const float dd = (m1v - m0) * (1.0f / 6.0f);
        const float res = y0 + tt * (bb + tt * (cc + tt * dd));
        __builtin_nontemporal_store(res, &o[j]);
    }
}

extern "C" void kernel_launch(void* const* d_in, const int* in_sizes, int n_in,
                              void* d_out, int out_size, void* d_ws, size_t ws_size,
                              hipStream_t stream) {
    const float* x     = (const float*)d_in[0];
    const float* scale = (const float*)d_in[1];
    const int*   mask  = (const int*)d_in[2];
    float*       out   = (float*)d_out;

    const int B     = in_sizes[1];            // 128
    const int total = in_sizes[0];            // B*C*S
    const int C     = total / (B * SLEN);     // 64
    const int nblk  = B * C;                  // 8192

    time_warp_kernel<<<nblk, BLK, 0, stream>>>(x, scale, mask, out, C);
}

// Round 8
// 234.233 us; speedup vs baseline: 1.4311x; 1.0150x over previous
//
#include <hip/hip_runtime.h>
#include <math.h>

// TIME_WARPING: not-a-knot cubic spline fit + warped resample, fused.
//
// Math: spline A M = rhs with M1 = y0-2y1+y2 (exact), MS2 = y[S-3]-2y[S-2]+y[S-1]
//   (exact), M0 = 2M1-M2, M[S-1] = 2MS2-M[S-3]; interior Toeplitz(1,4,1) inverse
//   = conv with G(k) = (-1)^k r^k/(2 sqrt3), r = 2-sqrt(3). Interior M == conv of
//   y with H = 6*(G (*) [1,-2,1]) truncated at WC=6 (validated R7: absmax
//   0.015625, identical to W=8). Edge region: exact f-based conv (W=8) + image
//   corrections (ghost v1/vS2) -- verbatim from the harness-verified R3 path.
//
// R8 = R3 structure + interleaved (y,M) pairs for pass D:
//  * sym2[i] = (y_i, M_i) float2 array. Pass D operand set (y0,m0,y1,m1) = 16
//    contiguous bytes at 8*idx -> ONE ds_read2_b64 (lane stride ~8B -> banks
//    2l,2l+1: conflict-free per 16-lane phase) instead of ~4 scattered reads.
//  * Pass C writes pairs from registers it already has (y in conv window, M
//    just computed): two aligned b128 stores per group.
//  * Interior conv W=6 (R7-validated accuracy), 4-wide groups with 16B-stride
//    windows (R3's proven conflict-free pattern): 5 b128 reads per group.
//  * LDS 48KB (sy 16K + sym2 32K) -> 3 blocks/CU; R0->R3 showed 3 vs 5
//    blocks/CU is perf-neutral here.
// Record: R4 persistence/prefetch, R5 conv-in-gather-space, R6 input-space
// transpose, R7 8-wide groups -- all neutral-to-regressive. Headline pinned at
// 233-238 across them; this tests the last quantitative model (LDS-pipe bound).

#define SLEN 4096
#define WRAD 8   // edge-path truncation (exact harness-verified path)
#define WC   6   // interior truncation (R7-validated)
#define BLK  256

typedef float f32x4 __attribute__((ext_vector_type(4)));

__global__ __launch_bounds__(BLK, 3) void time_warp_kernel(
    const float* __restrict__ x,
    const float* __restrict__ scale,
    const int*   __restrict__ apply_mask,
    float* __restrict__ out,
    int C)
{
    __shared__ float  sy[SLEN];     // input signal (conv source)     16384 B
    __shared__ float2 sym2[SLEN];   // interleaved (y, M) pairs       32768 B

    const int bid = blockIdx.x;   // = b*C + c
    const int b   = bid / C;
    const int t   = threadIdx.x;
    const float* __restrict__ xin = x   + (size_t)bid * SLEN;
    float*       __restrict__ o   = out + (size_t)bid * SLEN;

    // per-sample apply decision (block-uniform, before any barrier)
    if (apply_mask[b] == 0) {
        const f32x4* __restrict__ xi4 = (const f32x4*)xin;
        f32x4*       __restrict__ o4  = (f32x4*)o;
        #pragma unroll
        for (int k = 0; k < 4; ++k) {
            f32x4 v = xi4[t + BLK * k];
            __builtin_nontemporal_store(v, &o4[t + BLK * k]);
        }
        return;
    }

    // ---- stage y into LDS (coalesced float4 -> ds_write_b128) ----
    {
        const float4* __restrict__ xi4 = (const float4*)xin;
        #pragma unroll
        for (int k = 0; k < 4; ++k)
            *(float4*)&sy[4 * (t + BLK * k)] = xi4[t + BLK * k];
    }
    __syncthreads();

    // Green taps (compile-time folded). G: edge path (W=8) + H construction.
    const float r = 0.26794919243112270f;  // 2 - sqrt(3)
    float G[WRAD + 1];
    G[0] = 0.28867513459481287f;           // 1 / (2 sqrt(3))
    #pragma unroll
    for (int k = 1; k <= WRAD; ++k) G[k] = -G[k - 1] * r;
    // interior taps: H = 6*(G (*) [1,-2,1]) truncated at WC
    float Hh[WC + 2];
    Hh[0] = 12.0f * (G[1] - G[0]);
    #pragma unroll
    for (int k = 1; k < WC; ++k) Hh[k] = 6.0f * (G[k - 1] - 2.0f * G[k] + G[k + 1]);
    Hh[WC]     = 6.0f * (G[WC - 1] - 2.0f * G[WC]);   // G[WC+1] treated as 0
    Hh[WC + 1] = 6.0f * G[WC];
    const float log2r = -1.8999686269529532f;  // log2(2 - sqrt(3))

    // ---- pass C: M = conv(y); write (y,M) pairs to sym2 ----
    #pragma unroll
    for (int s = 0; s < 4; ++s) {
        const int j0 = 4 * t + 1024 * s;
        if (j0 >= 36 && j0 <= SLEN - 44) {
            // interior: window y[j0-8 .. j0+11], 5 aligned b128 reads,
            // lane stride 16B (R3's proven conflict-free pattern).
            float wv[20];
            #pragma unroll
            for (int m = 0; m < 5; ++m)
                *(float4*)&wv[4 * m] = *(const float4*)&sy[j0 - 8 + 4 * m];
            float mv[4];
            #pragma unroll
            for (int e = 0; e < 4; ++e) {      // y[j0+e] = wv[8+e]
                float acc = Hh[0] * wv[8 + e];
                #pragma unroll
                for (int k = 1; k <= WC + 1; ++k)
                    acc += Hh[k] * (wv[8 + e - k] + wv[8 + e + k]);
                mv[e] = acc;
            }
            // pairs (y,M): two aligned b128 stores at byte 8*j0 (32B-aligned)
            *(float4*)&sym2[j0]     = make_float4(wv[8],  mv[0], wv[9],  mv[1]);
            *(float4*)&sym2[j0 + 2] = make_float4(wv[10], mv[2], wv[11], mv[3]);
        } else {
            // edge path (~10 threads/block): exact f-based conv (W=8) + images,
            // verbatim R3 math.
            const float M1  = sy[0]        - 2.0f * sy[1]        + sy[2];
            const float MS2 = sy[SLEN - 3] - 2.0f * sy[SLEN - 2] + sy[SLEN - 1];

            float v1 = 0.0f, vS2 = 0.0f;
            #pragma unroll
            for (int k = 1; k <= WRAD; ++k) {
                const int ja = 1 + k;                        // 2..9
                float fa = 6.0f * (sy[ja - 1] - 2.0f * sy[ja] + sy[ja + 1]);
                if (ja == 2) fa -= M1;
                v1 += G[k] * fa;
                const int jb = SLEN - 2 - k;                 // S-3 .. S-10
                float fb = 6.0f * (sy[jb - 1] - 2.0f * sy[jb] + sy[jb + 1]);
                if (jb == SLEN - 3) fb -= MS2;
                vS2 += G[k] * fb;
            }

            float wv[28];                  // y[j0-12 .. j0+15], guarded quads
            #pragma unroll
            for (int m = 0; m < 7; ++m) {
                const int q = j0 - 12 + 4 * m;
                float4 v = make_float4(0.0f, 0.0f, 0.0f, 0.0f);
                if (q >= 0 && q <= SLEN - 4) v = *(const float4*)&sy[q];
                *(float4*)&wv[4 * m] = v;
            }
            float fw[20];                  // f[j0-8 .. j0+11]
            #pragma unroll
            for (int p = 0; p < 20; ++p) {
                const int jj = j0 + p - 8;
                float fv = 6.0f * (wv[p + 3] - 2.0f * wv[p + 4] + wv[p + 5]);
                if (jj < 2 || jj > SLEN - 3) fv = 0.0f;
                if (jj == 2)        fv -= M1;
                if (jj == SLEN - 3) fv -= MS2;
                fw[p] = fv;
            }
            float mv[4];
            #pragma unroll
            for (int e = 0; e < 4; ++e) {
                float acc = G[0] * fw[8 + e];
                #pragma unroll
                for (int k = 1; k <= WRAD; ++k)
                    acc += G[k] * (fw[8 + e - k] + fw[8 + e + k]);
                const int i = j0 + e;
                if (i >= 2 && i <= 34) {
                    float cc = v1 * exp2f((float)(i - 1) * log2r);
                    acc += (i & 1) ? -cc : cc;
                }
                if (i >= SLEN - 36 && i <= SLEN - 3) {
                    float cc = vS2 * exp2f((float)(SLEN - 2 - i) * log2r);
                    acc += (i & 1) ? cc : -cc;
                }
                mv[e] = acc;
            }
            if (j0 == 0)        { mv[1] = M1;  mv[0] = 2.0f * M1  - mv[2]; }
            if (j0 == SLEN - 4) { mv[2] = MS2; mv[3] = 2.0f * MS2 - mv[1]; }
            *(float4*)&sym2[j0]     = make_float4(wv[12], mv[0], wv[13], mv[1]);
            *(float4*)&sym2[j0 + 2] = make_float4(wv[14], mv[2], wv[15], mv[3]);
        }
    }
    __syncthreads();

    // ---- pass D: warped evaluation. One ds_read2_b64 per output:
    // (y0,m0) = sym2[idx], (y1,m1) = sym2[idx+1] -- 16 contiguous bytes.
    // Interleaved mapping j = t + 256*q: lane byte-stride ~8 -> banks 2l,2l+1,
    // conflict-free per 16-lane phase. Scalar NT stores, perfectly coalesced.
    const float sc = scale[b];
    #pragma unroll
    for (int q = 0; q < 16; ++q) {
        const int j = t + BLK * q;
        float w = fminf((float)j * sc, (float)(SLEN - 1));
        int idx = (int)w;
        if (idx > SLEN - 2) idx = SLEN - 2;
        const float tt = w - (float)idx;
        const float2 p0 = sym2[idx];
        const float2 p1 = sym2[idx + 1];
        const float y0 = p0.x, m0 = p0.y;
        const float y1 = p1.x, m1 = p1.y;
        const float bb = (y1 - y0) - (2.0f * m0 + m1) * (1.0f / 6.0f);
        const float cc = 0.5f * m0;
        const float dd = (m1 - m0) * (1.0f / 6.0f);
        const float res = y0 + tt * (bb + tt * (cc + tt * dd));
        __builtin_nontemporal_store(res, &o[j]);
    }
}

extern "C" void kernel_launch(void* const* d_in, const int* in_sizes, int n_in,
                              void* d_out, int out_size, void* d_ws, size_t ws_size,
                              hipStream_t stream) {
    const float* x     = (const float*)d_in[0];
    const float* scale = (const float*)d_in[1];
    const int*   mask  = (const int*)d_in[2];
    float*       out   = (float*)d_out;

    const int B     = in_sizes[1];            // 128
    const int total = in_sizes[0];            // B*C*S
    const int C     = total / (B * SLEN);     // 64
    const int nblk  = B * C;                  // 8192

    time_warp_kernel<<<nblk, BLK, 0, stream>>>(x, scale, mask, out, C);
}

// Round 11
// 233.757 us; speedup vs baseline: 1.4340x; 1.0020x over previous
//
#include <hip/hip_runtime.h>
#include <math.h>

// TIME_WARPING: not-a-knot cubic spline fit + warped resample, fused.
//
// Math: spline A M = rhs with M1 = y0-2y1+y2 (exact), MS2 = y[S-3]-2y[S-2]+y[S-1]
//   (exact), M0 = 2M1-M2, M[S-1] = 2MS2-M[S-3]; interior Toeplitz(1,4,1) inverse
//   = conv with G(k) = (-1)^k r^k/(2 sqrt3), r = 2-sqrt(3). Interior M == conv of
//   y with H = 6*(G (*) [1,-2,1]) truncated at WC=6 (R7/R8-validated: absmax
//   0.015625 == W=8). Edge region: exact f-based conv (W=8) + image corrections.
//
// R11 = R9/R10 resubmission (two GPU-acquisition timeouts; never measured):
//  * All prior levers (LDS size, conflicts, barriers, persistence, VALU trims,
//    LDS instr count) are falsified: headline pinned 233-238 with all pipes
//    <35%. Remaining model: latency-bound with only 12-20/32 wave-slots
//    resident (256-thr blocks; VGPR 68 capped waves at 7/SIMD).
//  * BLK=1024: per-thread serial work /4 (1 staging float4, 1 conv group,
//    4 pass-D outputs); __launch_bounds__(1024,8) forces VGPR<=64 so
//    2 blocks x 16 waves = 32 waves/CU = 100% wave-slot occupancy.
//  * sym2 (y,M)-interleaved pairs (R8: lowest conflicts, best per-dispatch):
//    pass D reads 16 contiguous bytes per output (ds_read2_b64-friendly).

#define SLEN 4096
#define WRAD 8   // edge-path truncation (exact harness-verified path)
#define WC   6   // interior truncation (R7/R8-validated)
#define BLK  1024

typedef float f32x4 __attribute__((ext_vector_type(4)));

__global__ __launch_bounds__(BLK, 8) void time_warp_kernel(
    const float* __restrict__ x,
    const float* __restrict__ scale,
    const int*   __restrict__ apply_mask,
    float* __restrict__ out,
    int C)
{
    __shared__ float  sy[SLEN];     // input signal (conv source)     16384 B
    __shared__ float2 sym2[SLEN];   // interleaved (y, M) pairs       32768 B

    const int bid = blockIdx.x;   // = b*C + c
    const int b   = bid / C;
    const int t   = threadIdx.x;
    const float* __restrict__ xin = x   + (size_t)bid * SLEN;
    float*       __restrict__ o   = out + (size_t)bid * SLEN;

    // per-sample apply decision (block-uniform, before any barrier)
    if (apply_mask[b] == 0) {
        const f32x4* __restrict__ xi4 = (const f32x4*)xin;
        f32x4*       __restrict__ o4  = (f32x4*)o;
        f32x4 v = xi4[t];
        __builtin_nontemporal_store(v, &o4[t]);
        return;
    }

    // ---- stage y into LDS: ONE float4 per thread (16B lane stride) ----
    {
        const float4* __restrict__ xi4 = (const float4*)xin;
        *(float4*)&sy[4 * t] = xi4[t];
    }
    __syncthreads();

    // Green taps (compile-time folded). G: edge path (W=8) + H construction.
    const float r = 0.26794919243112270f;  // 2 - sqrt(3)
    float G[WRAD + 1];
    G[0] = 0.28867513459481287f;           // 1 / (2 sqrt(3))
    #pragma unroll
    for (int k = 1; k <= WRAD; ++k) G[k] = -G[k - 1] * r;
    // interior taps: H = 6*(G (*) [1,-2,1]) truncated at WC
    float Hh[WC + 2];
    Hh[0] = 12.0f * (G[1] - G[0]);
    #pragma unroll
    for (int k = 1; k < WC; ++k) Hh[k] = 6.0f * (G[k - 1] - 2.0f * G[k] + G[k + 1]);
    Hh[WC]     = 6.0f * (G[WC - 1] - 2.0f * G[WC]);   // G[WC+1] treated as 0
    Hh[WC + 1] = 6.0f * G[WC];
    const float log2r = -1.8999686269529532f;  // log2(2 - sqrt(3))

    // ---- pass C: ONE 4-wide group per thread; write (y,M) pairs to sym2 ----
    {
        const int j0 = 4 * t;
        if (j0 >= 36 && j0 <= SLEN - 44) {
            // interior: window y[j0-8 .. j0+11], 5 aligned b128 reads,
            // lane stride 16B (proven conflict-free pattern).
            float wv[20];
            #pragma unroll
            for (int m = 0; m < 5; ++m)
                *(float4*)&wv[4 * m] = *(const float4*)&sy[j0 - 8 + 4 * m];
            float mv[4];
            #pragma unroll
            for (int e = 0; e < 4; ++e) {      // y[j0+e] = wv[8+e]
                float acc = Hh[0] * wv[8 + e];
                #pragma unroll
                for (int k = 1; k <= WC + 1; ++k)
                    acc += Hh[k] * (wv[8 + e - k] + wv[8 + e + k]);
                mv[e] = acc;
            }
            // pairs (y,M): two aligned b128 stores at byte 8*j0 (32B-aligned)
            *(float4*)&sym2[j0]     = make_float4(wv[8],  mv[0], wv[9],  mv[1]);
            *(float4*)&sym2[j0 + 2] = make_float4(wv[10], mv[2], wv[11], mv[3]);
        } else {
            // edge path (~19 lanes total, waves 0 and 15): exact f-based conv
            // (W=8) + image corrections, verbatim harness-verified math.
            const float M1  = sy[0]        - 2.0f * sy[1]        + sy[2];
            const float MS2 = sy[SLEN - 3] - 2.0f * sy[SLEN - 2] + sy[SLEN - 1];

            float v1 = 0.0f, vS2 = 0.0f;
            #pragma unroll
            for (int k = 1; k <= WRAD; ++k) {
                const int ja = 1 + k;                        // 2..9
                float fa = 6.0f * (sy[ja - 1] - 2.0f * sy[ja] + sy[ja + 1]);
                if (ja == 2) fa -= M1;
                v1 += G[k] * fa;
                const int jb = SLEN - 2 - k;                 // S-3 .. S-10
                float fb = 6.0f * (sy[jb - 1] - 2.0f * sy[jb] + sy[jb + 1]);
                if (jb == SLEN - 3) fb -= MS2;
                vS2 += G[k] * fb;
            }

            float wv[28];                  // y[j0-12 .. j0+15], guarded quads
            #pragma unroll
            for (int m = 0; m < 7; ++m) {
                const int q = j0 - 12 + 4 * m;
                float4 v = make_float4(0.0f, 0.0f, 0.0f, 0.0f);
                if (q >= 0 && q <= SLEN - 4) v = *(const float4*)&sy[q];
                *(float4*)&wv[4 * m] = v;
            }
            float fw[20];                  // f[j0-8 .. j0+11]
            #pragma unroll
            for (int p = 0; p < 20; ++p) {
                const int jj = j0 + p - 8;
                float fv = 6.0f * (wv[p + 3] - 2.0f * wv[p + 4] + wv[p + 5]);
                if (jj < 2 || jj > SLEN - 3) fv = 0.0f;
                if (jj == 2)        fv -= M1;
                if (jj == SLEN - 3) fv -= MS2;
                fw[p] = fv;
            }
            float mv[4];
            #pragma unroll
            for (int e = 0; e < 4; ++e) {
                float acc = G[0] * fw[8 + e];
                #pragma unroll
                for (int k = 1; k <= WRAD; ++k)
                    acc += G[k] * (fw[8 + e - k] + fw[8 + e + k]);
                const int i = j0 + e;
                if (i >= 2 && i <= 34) {
                    float cc = v1 * exp2f((float)(i - 1) * log2r);
                    acc += (i & 1) ? -cc : cc;
                }
                if (i >= SLEN - 36 && i <= SLEN - 3) {
                    float cc = vS2 * exp2f((float)(SLEN - 2 - i) * log2r);
                    acc += (i & 1) ? cc : -cc;
                }
                mv[e] = acc;
            }
            if (j0 == 0)        { mv[1] = M1;  mv[0] = 2.0f * M1  - mv[2]; }
            if (j0 == SLEN - 4) { mv[2] = MS2; mv[3] = 2.0f * MS2 - mv[1]; }
            *(float4*)&sym2[j0]     = make_float4(wv[12], mv[0], wv[13], mv[1]);
            *(float4*)&sym2[j0 + 2] = make_float4(wv[14], mv[2], wv[15], mv[3]);
        }
    }
    __syncthreads();

    // ---- pass D: warped evaluation, 4 outputs/thread, j = t + 1024*q ----
    // (y0,m0,y1,m1) = 16 contiguous bytes at sym2[idx] -> ds_read2_b64;
    // consecutive lanes -> consecutive idx (conflict-light); NT scalar stores,
    // perfectly coalesced (256B per wave-instr).
    const float sc = scale[b];
    #pragma unroll
    for (int q = 0; q < 4; ++q) {
        const int j = t + BLK * q;
        float w = fminf((float)j * sc, (float)(SLEN - 1));
        int idx = (int)w;
        if (idx > SLEN - 2) idx = SLEN - 2;
        const float tt = w - (float)idx;
        const float2 p0 = sym2[idx];
        const float2 p1 = sym2[idx + 1];
        const float y0 = p0.x, m0 = p0.y;
        const float y1 = p1.x, m1 = p1.y;
        const float bb = (y1 - y0) - (2.0f * m0 + m1) * (1.0f / 6.0f);
        const float cc = 0.5f * m0;
        const float dd = (m1 - m0) * (1.0f / 6.0f);
        const float res = y0 + tt * (bb + tt * (cc + tt * dd));
        __builtin_nontemporal_store(res, &o[j]);
    }
}

extern "C" void kernel_launch(void* const* d_in, const int* in_sizes, int n_in,
                              void* d_out, int out_size, void* d_ws, size_t ws_size,
                              hipStream_t stream) {
    const float* x     = (const float*)d_in[0];
    const float* scale = (const float*)d_in[1];
    const int*   mask  = (const int*)d_in[2];
    float*       out   = (float*)d_out;

    const int B     = in_sizes[1];            // 128
    const int total = in_sizes[0];            // B*C*S
    const int C     = total / (B * SLEN);     // 64
    const int nblk  = B * C;                  // 8192

    time_warp_kernel<<<nblk, BLK, 0, stream>>>(x, scale, mask, out, C);
}